// Round 5
// baseline (185.619 us; speedup 1.0000x reference)
//
#include <hip/hip_runtime.h>
#include <stdint.h>

// Fused binary-morphology skeleton kernel.
// x==1 predicate is sufficient: erode test (conv>=ksum) with unit weights and
// values <=1 is "all support pixels ==1"; update b &= ~dilate(mask).
// All 8 structuring elements are axis-aligned rectangles -> separable
// erode (AND) / dilate (OR). Each block ballot-packs its own input strip
// (+16-row halo) into LDS and runs the whole 8-step chain + isolated-point.

typedef unsigned long long u64;
typedef float vfloat4 __attribute__((ext_vector_type(4)));   // native vec for nontemporal

#define WIDTH   1024
#define HEIGHT  1024
#define NIMG    16
#define WPR     16          // u64 words per image row
#define TH      32          // output rows per block
#define HALO    16
#define RR      (TH + 2 * HALO)   // 64 region rows
#define PR      (RR + 2)    // padded rows (zero ring)
#define PW      18          // padded words (zero ring)
#define NTHR    256

// ---------------- bit-parallel separable helpers (LSB = leftmost pixel) -------
template <int CM>
__device__ __forceinline__ u64 hand(const u64* Ar, int w) {
    u64 c = Ar[w], res = ~0ULL;
    if (CM & 2) res &= c;
    if (CM & 1) res &= (c << 1) | (Ar[w - 1] >> 63);   // sample x-1
    if (CM & 4) res &= (c >> 1) | (Ar[w + 1] << 63);   // sample x+1
    return res;
}
template <int CM>
__device__ __forceinline__ u64 hor(const u64* Ar, int w) {
    u64 c = Ar[w], res = 0;
    if (CM & 2) res |= c;
    if (CM & 1) res |= (c >> 1) | (Ar[w + 1] << 63);   // sample x+1
    if (CM & 4) res |= (c << 1) | (Ar[w - 1] >> 63);   // sample x-1
    return res;
}
template <int RM>
__device__ __forceinline__ u64 vand(const u64 (*A)[PW], int r, int w) {
    u64 res = ~0ULL;
    if (RM & 1) res &= A[r - 1][w];
    if (RM & 2) res &= A[r][w];
    if (RM & 4) res &= A[r + 1][w];
    return res;
}
template <int RM>
__device__ __forceinline__ u64 vor(const u64 (*A)[PW], int r, int w) {
    u64 res = 0;
    if (RM & 1) res |= A[r + 1][w];
    if (RM & 2) res |= A[r][w];
    if (RM & 4) res |= A[r - 1][w];
    return res;
}

// Apply f(r,w) to all cells within row-radius R of the tile (tile = padded
// rows 17..17+TH-1), full width (padded words 1..16). Barrier afterwards.
template <int R, typename F>
__device__ __forceinline__ void forcells(F f) {
    for (int idx = threadIdx.x; idx < (TH + 2 * R) * WPR; idx += NTHR) {
        int r = 17 - R + (idx >> 4);
        int w = 1 + (idx & 15);
        f(r, w);
    }
    __syncthreads();
}

// One skeleton step: M = erode(B,S); O |= M; B &= ~dilate(M, reflect(S)).
template <int RM, int CM, int HR, int MR, int DHR, int BR, bool DIL>
__device__ __forceinline__ void morph_step(u64 (&B)[PR][PW], u64 (&T)[PR][PW],
                                           u64 (&M)[PR][PW], u64 (&O)[PR][PW]) {
    if (CM != 2 && RM != 2) {
        forcells<HR>([&](int r, int w) { T[r][w] = hand<CM>(B[r], w); });
        forcells<MR>([&](int r, int w) {
            u64 m = vand<RM>(T, r, w); M[r][w] = m; O[r][w] |= m;
        });
    } else if (CM == 2) {            // column-only kernel
        forcells<MR>([&](int r, int w) {
            u64 m = vand<RM>(B, r, w); M[r][w] = m; O[r][w] |= m;
        });
    } else {                         // row-only kernel
        forcells<MR>([&](int r, int w) {
            u64 m = hand<CM>(B[r], w); M[r][w] = m; O[r][w] |= m;
        });
    }
    if (DIL) {
        if (CM != 2 && RM != 2) {
            forcells<DHR>([&](int r, int w) { T[r][w] = hor<CM>(M[r], w); });
            forcells<BR>([&](int r, int w) { B[r][w] &= ~vor<RM>(T, r, w); });
        } else if (CM == 2) {
            forcells<BR>([&](int r, int w) { B[r][w] &= ~vor<RM>(M, r, w); });
        } else {
            forcells<BR>([&](int r, int w) { B[r][w] &= ~hor<CM>(M[r], w); });
        }
    }
}

// ---------------- fused: pack + 8-step morphology + isolated-point -----------
__global__ __launch_bounds__(NTHR) void skel_kernel(const float* __restrict__ x,
                                                    float* __restrict__ out) {
    __shared__ u64 B[PR][PW];
    __shared__ u64 T[PR][PW];
    __shared__ u64 M[PR][PW];
    __shared__ u64 O[PR][PW];
    int tid = threadIdx.x;
    int ty = blockIdx.x, img = blockIdx.y;

    // zero B, M, O (pads stay zero forever -> zero boundary)
    {
        u64* bf = &B[0][0]; u64* mf = &M[0][0]; u64* of = &O[0][0];
        for (int i = tid; i < PR * PW; i += NTHR) { bf[i] = 0; mf[i] = 0; of[i] = 0; }
    }
    __syncthreads();

    // pack input region directly: rows ty*TH-16 .. ty*TH+TH+15 (clipped)
    {
        int wv = tid >> 6, lane = tid & 63;
        const float* ximg = x + (size_t)img * HEIGHT * WIDTH;
        for (int rr = wv; rr < RR; rr += NTHR / 64) {
            int gy = ty * TH - HALO + rr;
            if (gy >= 0 && gy < HEIGHT) {
                const float* rbase = ximg + (size_t)gy * WIDTH + lane;
                #pragma unroll
                for (int w16 = 0; w16 < 16; ++w16) {
                    float f = rbase[w16 * 64];
                    u64 m = __ballot(f > 0.5f);   // bit i (LSB) = pixel w16*64+i
                    if (lane == 0) B[rr + 1][w16 + 1] = m;
                }
            }
        }
    }
    __syncthreads();

    // 8 structuring elements as (rowmask, colmask) rectangles; radii shrink 2/step
    morph_step<7, 7, 16, 15, 15, 14, true >(B, T, M, O);  // all ones
    morph_step<7, 6, 14, 13, 13, 12, true >(B, T, M, O);  // cols {1,2}
    morph_step<3, 7, 12, 11, 11, 10, true >(B, T, M, O);  // rows {0,1}
    morph_step<6, 6, 10,  9,  9,  8, true >(B, T, M, O);  // rows {1,2} x cols {1,2}
    morph_step<7, 2,  8,  7,  7,  6, true >(B, T, M, O);  // col {1}
    morph_step<2, 7,  6,  5,  5,  4, true >(B, T, M, O);  // row {1}
    morph_step<3, 2,  4,  3,  3,  2, true >(B, T, M, O);  // col {1}, rows {0,1}
    morph_step<2, 3,  2,  1,  1,  0, false>(B, T, M, O);  // row {1}, cols {0,1}

    // isolated-point: 3x3 popcount of O == 1 via carry-save (ones, sticky twos)
    forcells<0>([&](int r, int w) {
        u64 ones = 0;
        u64 twos = 0;
        #pragma unroll
        for (int dr = -1; dr <= 1; ++dr) {
            const u64* Ar = O[r + dr];
            u64 c  = Ar[w];
            u64 wv = (c << 1) | (Ar[w - 1] >> 63);
            u64 ev = (c >> 1) | (Ar[w + 1] << 63);
            twos |= ones & wv; ones ^= wv;
            twos |= ones & c;  ones ^= c;
            twos |= ones & ev; ones ^= ev;
        }
        T[r][w] = ones & ~twos;
    });

    // write float output, float4 nontemporal, coalesced
    float* obase = out + ((size_t)img * HEIGHT + (size_t)ty * TH) * WIDTH;
    for (int idx = tid; idx < TH * (WIDTH / 4); idx += NTHR) {
        int row = idx >> 8;           // 256 float4 groups per row
        int q   = idx & 255;
        u64 word = T[17 + row][1 + (q >> 4)];
        int b = (q & 15) * 4;
        vfloat4 v;
        v.x = (float)((word >> (b + 0)) & 1ULL);
        v.y = (float)((word >> (b + 1)) & 1ULL);
        v.z = (float)((word >> (b + 2)) & 1ULL);
        v.w = (float)((word >> (b + 3)) & 1ULL);
        __builtin_nontemporal_store(v, (vfloat4*)(obase + (size_t)row * WIDTH + q * 4));
    }
}

extern "C" void kernel_launch(void* const* d_in, const int* in_sizes, int n_in,
                              void* d_out, int out_size, void* d_ws, size_t ws_size,
                              hipStream_t stream) {
    const float* x = (const float*)d_in[0];
    float* out = (float*)d_out;
    hipLaunchKernelGGL(skel_kernel, dim3(HEIGHT / TH, NIMG), dim3(NTHR), 0, stream,
                       x, out);
}

// Round 6
// 117.353 us; speedup vs baseline: 1.5817x; 1.5817x over previous
//
#include <hip/hip_runtime.h>
#include <stdint.h>

// Two-kernel binary-morphology skeleton.
// Pack: float4 loads + nibble + shfl_xor OR-reduce -> 64px/word bitmask.
// Morph: separable rectangle erode/dilate in LDS, shrinking radii, TH=32
// strips (512 blocks, 2 resident/CU) for barrier-latency overlap.

typedef unsigned long long u64;
typedef float vfloat4 __attribute__((ext_vector_type(4)));

#define WIDTH   1024
#define HEIGHT  1024
#define NIMG    16
#define WPR     16          // u64 words per image row
#define TH      32          // output rows per morph block
#define HALO    16
#define RRROWS  64          // region rows = TH + 2*HALO
#define PR      66          // padded rows (zero ring)
#define PW      18          // padded words (zero ring)
#define NTHR    512         // morph block threads
#define PACK_ROWS 4         // rows per pack block (1 per wave)

// ---------------- phase 1: binarize + bit-pack, float4 + shfl assembly -------
__global__ __launch_bounds__(256) void pack_kernel(const float* __restrict__ x,
                                                   u64* __restrict__ packed) {
    int wv = threadIdx.x >> 6, lane = threadIdx.x & 63;
    int row = blockIdx.x * PACK_ROWS + wv;        // one image row per wave
    const float* rbase = x + (size_t)row * WIDTH;
    u64* pbase = packed + (size_t)row * WPR;
    #pragma unroll
    for (int rnd = 0; rnd < 4; ++rnd) {           // 256 px per round
        vfloat4 v = *(const vfloat4*)(rbase + rnd * 256 + lane * 4);
        unsigned nib = (v.x > 0.5f ? 1u : 0u) | (v.y > 0.5f ? 2u : 0u)
                     | (v.z > 0.5f ? 4u : 0u) | (v.w > 0.5f ? 8u : 0u);
        u64 n = (u64)nib << (4 * (lane & 15));
        n |= __shfl_xor(n, 1);                    // OR-reduce within 16-lane
        n |= __shfl_xor(n, 2);                    // groups: group g holds
        n |= __shfl_xor(n, 4);                    // px 256*rnd+64g..+63
        n |= __shfl_xor(n, 8);
        if ((lane & 15) == 0) pbase[rnd * 4 + (lane >> 4)] = n;
    }
}

// ---------------- bit-parallel separable helpers (LSB = leftmost pixel) -------
template <int CM>
__device__ __forceinline__ u64 hand(const u64* Ar, int w) {
    u64 c = Ar[w], res = ~0ULL;
    if (CM & 2) res &= c;
    if (CM & 1) res &= (c << 1) | (Ar[w - 1] >> 63);   // sample x-1
    if (CM & 4) res &= (c >> 1) | (Ar[w + 1] << 63);   // sample x+1
    return res;
}
template <int CM>
__device__ __forceinline__ u64 hor(const u64* Ar, int w) {
    u64 c = Ar[w], res = 0;
    if (CM & 2) res |= c;
    if (CM & 1) res |= (c >> 1) | (Ar[w + 1] << 63);   // sample x+1
    if (CM & 4) res |= (c << 1) | (Ar[w - 1] >> 63);   // sample x-1
    return res;
}
template <int RM>
__device__ __forceinline__ u64 vand(const u64 (*A)[PW], int r, int w) {
    u64 res = ~0ULL;
    if (RM & 1) res &= A[r - 1][w];
    if (RM & 2) res &= A[r][w];
    if (RM & 4) res &= A[r + 1][w];
    return res;
}
template <int RM>
__device__ __forceinline__ u64 vor(const u64 (*A)[PW], int r, int w) {
    u64 res = 0;
    if (RM & 1) res |= A[r + 1][w];
    if (RM & 2) res |= A[r][w];
    if (RM & 4) res |= A[r - 1][w];
    return res;
}

// Apply f(r,w) to all cells within row-radius R of the tile (tile = padded
// rows 17..17+TH-1), full width (padded words 1..16). Barrier afterwards.
template <int R, typename F>
__device__ __forceinline__ void forcells(F f) {
    for (int idx = threadIdx.x; idx < (TH + 2 * R) * WPR; idx += NTHR) {
        int r = 17 - R + (idx >> 4);
        int w = 1 + (idx & 15);
        f(r, w);
    }
    __syncthreads();
}

// One skeleton step: M = erode(B,S); O |= M; B &= ~dilate(M, reflect(S)).
template <int RM, int CM, int HR, int MR, int DHR, int BR, bool DIL>
__device__ __forceinline__ void morph_step(u64 (&B)[PR][PW], u64 (&T)[PR][PW],
                                           u64 (&M)[PR][PW], u64 (&O)[PR][PW]) {
    if (CM != 2 && RM != 2) {
        forcells<HR>([&](int r, int w) { T[r][w] = hand<CM>(B[r], w); });
        forcells<MR>([&](int r, int w) {
            u64 m = vand<RM>(T, r, w); M[r][w] = m; O[r][w] |= m;
        });
    } else if (CM == 2) {            // column-only kernel
        forcells<MR>([&](int r, int w) {
            u64 m = vand<RM>(B, r, w); M[r][w] = m; O[r][w] |= m;
        });
    } else {                         // row-only kernel
        forcells<MR>([&](int r, int w) {
            u64 m = hand<CM>(B[r], w); M[r][w] = m; O[r][w] |= m;
        });
    }
    if (DIL) {
        if (CM != 2 && RM != 2) {
            forcells<DHR>([&](int r, int w) { T[r][w] = hor<CM>(M[r], w); });
            forcells<BR>([&](int r, int w) { B[r][w] &= ~vor<RM>(T, r, w); });
        } else if (CM == 2) {
            forcells<BR>([&](int r, int w) { B[r][w] &= ~vor<RM>(M, r, w); });
        } else {
            forcells<BR>([&](int r, int w) { B[r][w] &= ~hor<CM>(M[r], w); });
        }
    }
}

// ---------------- phase 2: 8-step morphology + isolated-point ----------------
__global__ __launch_bounds__(NTHR) void morph_kernel(const u64* __restrict__ packed,
                                                     float* __restrict__ out) {
    __shared__ u64 B[PR][PW];
    __shared__ u64 T[PR][PW];
    __shared__ u64 M[PR][PW];
    __shared__ u64 O[PR][PW];
    int tid = threadIdx.x;
    int ty = blockIdx.x, img = blockIdx.y;

    // zero B, M, O (pads stay zero forever -> zero boundary); T needs no init
    {
        u64* bf = &B[0][0]; u64* mf = &M[0][0]; u64* of = &O[0][0];
        for (int i = tid; i < PR * PW; i += NTHR) { bf[i] = 0; mf[i] = 0; of[i] = 0; }
    }
    __syncthreads();

    // load region: rows ty*TH-16 .. ty*TH+TH+15 (clipped), full width
    const u64* pimg = packed + (size_t)img * HEIGHT * WPR;
    for (int idx = tid; idx < RRROWS * WPR; idx += NTHR) {
        int rr = idx >> 4, w = idx & 15;
        int gy = ty * TH - HALO + rr;
        if (gy >= 0 && gy < HEIGHT)
            B[rr + 1][w + 1] = pimg[(size_t)gy * WPR + w];
    }
    __syncthreads();

    // 8 structuring elements as (rowmask, colmask) rectangles; radii shrink 2/step
    morph_step<7, 7, 16, 15, 15, 14, true >(B, T, M, O);  // all ones
    morph_step<7, 6, 14, 13, 13, 12, true >(B, T, M, O);  // cols {1,2}
    morph_step<3, 7, 12, 11, 11, 10, true >(B, T, M, O);  // rows {0,1}
    morph_step<6, 6, 10,  9,  9,  8, true >(B, T, M, O);  // rows {1,2} x cols {1,2}
    morph_step<7, 2,  8,  7,  7,  6, true >(B, T, M, O);  // col {1}
    morph_step<2, 7,  6,  5,  5,  4, true >(B, T, M, O);  // row {1}
    morph_step<3, 2,  4,  3,  3,  2, true >(B, T, M, O);  // col {1}, rows {0,1}
    morph_step<2, 3,  2,  1,  1,  0, false>(B, T, M, O);  // row {1}, cols {0,1}

    // isolated-point: 3x3 popcount of O == 1 via carry-save (ones, sticky twos)
    forcells<0>([&](int r, int w) {
        u64 ones = 0;
        u64 twos = 0;
        #pragma unroll
        for (int dr = -1; dr <= 1; ++dr) {
            const u64* Ar = O[r + dr];
            u64 c  = Ar[w];
            u64 wv = (c << 1) | (Ar[w - 1] >> 63);
            u64 ev = (c >> 1) | (Ar[w + 1] << 63);
            twos |= ones & wv; ones ^= wv;
            twos |= ones & c;  ones ^= c;
            twos |= ones & ev; ones ^= ev;
        }
        T[r][w] = ones & ~twos;
    });

    // write float output, float4 nontemporal, coalesced
    float* obase = out + ((size_t)img * HEIGHT + (size_t)ty * TH) * WIDTH;
    for (int idx = tid; idx < TH * (WIDTH / 4); idx += NTHR) {
        int row = idx >> 8;           // 256 float4 groups per row
        int q   = idx & 255;
        u64 word = T[17 + row][1 + (q >> 4)];
        int b = (q & 15) * 4;
        vfloat4 v;
        v.x = (float)((word >> (b + 0)) & 1ULL);
        v.y = (float)((word >> (b + 1)) & 1ULL);
        v.z = (float)((word >> (b + 2)) & 1ULL);
        v.w = (float)((word >> (b + 3)) & 1ULL);
        __builtin_nontemporal_store(v, (vfloat4*)(obase + (size_t)row * WIDTH + q * 4));
    }
}

extern "C" void kernel_launch(void* const* d_in, const int* in_sizes, int n_in,
                              void* d_out, int out_size, void* d_ws, size_t ws_size,
                              hipStream_t stream) {
    const float* x = (const float*)d_in[0];
    float* out = (float*)d_out;
    u64* packed = (u64*)d_ws;   // NIMG*HEIGHT*WPR*8 = 2 MiB used

    hipLaunchKernelGGL(pack_kernel, dim3(NIMG * HEIGHT / PACK_ROWS), dim3(256), 0,
                       stream, x, packed);
    hipLaunchKernelGGL(morph_kernel, dim3(HEIGHT / TH, NIMG), dim3(NTHR), 0, stream,
                       packed, out);
}